// Round 6
// baseline (1550.882 us; speedup 1.0000x reference)
//
#include <hip/hip_runtime.h>
#include <hip/hip_bf16.h>

// ---------------------------------------------------------------------------
// myLSTM R6: exchange-free scan; pinned 2 waves/EU (256-VGPR budget) and a
// rebalanced Wh partition: 4 reg tiles + 2-3 LDS tiles + 1-2 streamed tiles
// per wave.
//
// R2-R5 lesson: bf16 Wh = 512KB = the ENTIRE CU register file; every
// partition needing 93-105% of the per-wave cap got spilled by the
// allocator (which also freely picks a HIGHER occupancy than
// __launch_bounds__'s minimum: R5 asked (512,2) and got 128 regs = 4/EU).
// R6 pins occupancy with amdgpu_waves_per_eu(2,2) and budgets 84% of cap:
//   frA 4 tiles = 128 + hb8 32 + sb 32 + acc 8 + misc ~16 = ~217 / 256.
// LDS: 19 tiles x 8KB = 152KB (+1KB hA). Streams: 13 tiles = 104KB/step
// from L2 (~1200-1900cy) -- the step bound; MFMA floor 640cy/SIMD.
//
//   prep_all  : x->bf16 ; Wi -> WiT [1024][256] bf16 ; Wh -> WhP permuted
//               [1024][256] bf16, row' = w*128 + rt*16 + q*4 + r  <->
//               col_nat = gate(r)*256 + unit(w*32 + rt*4 + q).
//   xg_gemm   : xg = x@Wi + b (bf16 MFMA 128x128), PERMUTED [b][t][u][gate].
//   lstm_scan : 64 WGs (one batch each), 512 thr = 8 waves, 2/SIMD pinned.
//               Wave w owns Wh rows' [w*128,+128) = 8 tiles, pass p = tile:
//               p 0..nS-1 streamed (nS=1 for waves 0-2, else 2; single sb
//               buffer, tile-0 prefetched across the barrier under the gate
//               VALU, tile-1 issued mid-step), p nS..nS+3 register tiles,
//               p nS+4..7 LDS tiles (19 slots, XOR-swizzled). h_{t-1} (512B)
//               double-buffered in LDS, broadcast B-fragment. Extraction:
//               lane l16==p owns unit w*32 + l16*4 + quad. One barrier/step.
//   attn_head : fused attention + MLP head (block-local per batch).
// ---------------------------------------------------------------------------

typedef __attribute__((ext_vector_type(8))) short short8;   // 8 x bf16 (4 VGPR)
typedef __attribute__((ext_vector_type(4))) float float4v;  // MFMA acc

__device__ __forceinline__ unsigned short f2bf(float f) {  // RNE f32->bf16
  unsigned u = __builtin_bit_cast(unsigned, f);
  return (unsigned short)((u + 0x7fffu + ((u >> 16) & 1u)) >> 16);
}
__device__ __forceinline__ float bf2f(unsigned short h) {
  return __builtin_bit_cast(float, ((unsigned)h) << 16);
}
__device__ __forceinline__ float bcl(unsigned u) {  // low bf16 of dword
  return __builtin_bit_cast(float, u << 16);
}
__device__ __forceinline__ float bch(unsigned u) {  // high bf16 of dword
  return __builtin_bit_cast(float, u & 0xffff0000u);
}
// v_rcp_f32 (1 ulp) instead of precise div: error ~1e-7, invisible vs bf16.
__device__ __forceinline__ float sigm(float x) {
  return __builtin_amdgcn_rcpf(1.f + __expf(-x));
}
__device__ __forceinline__ float tanh_f(float x) {
  return 1.f - 2.f * __builtin_amdgcn_rcpf(1.f + __expf(2.f * x));
}

// ---------------------------------------------------------------- prep (fused)
// blocks [0,8192)    : x fp32 -> bf16                (8,388,608 elems)
// blocks [8192,8448) : Wi [256,1024] -> WiT [1024][256] bf16
// blocks [8448,8704) : Wh [256,1024] -> WhP [1024][256] bf16, row-permuted
__global__ void prep_all(const float* __restrict__ x,
                         const float* __restrict__ Wi,
                         const float* __restrict__ Wh,
                         unsigned short* __restrict__ xbf,
                         unsigned short* __restrict__ WiT,
                         unsigned short* __restrict__ WhP) {
  const int bid = blockIdx.x, tid = threadIdx.x;
  if (bid < 8192) {
    size_t i = ((size_t)bid * 256 + tid) * 4;
    float4 v = *(const float4*)&x[i];
    unsigned long long pk = (unsigned long long)f2bf(v.x)
                          | ((unsigned long long)f2bf(v.y) << 16)
                          | ((unsigned long long)f2bf(v.z) << 32)
                          | ((unsigned long long)f2bf(v.w) << 48);
    *(unsigned long long*)&xbf[i] = pk;
  } else if (bid < 8448) {
    size_t i = ((size_t)(bid - 8192) * 256 + tid) * 4;
    float4 v = *(const float4*)&Wi[i];
    int k = (int)(i >> 10), n = (int)(i & 1023);
    WiT[(size_t)(n + 0) * 256 + k] = f2bf(v.x);
    WiT[(size_t)(n + 1) * 256 + k] = f2bf(v.y);
    WiT[(size_t)(n + 2) * 256 + k] = f2bf(v.z);
    WiT[(size_t)(n + 3) * 256 + k] = f2bf(v.w);
  } else {
    size_t i0 = ((size_t)(bid - 8448) * 256 + tid) * 4;
    int row = (int)(i0 >> 8);  // row' (same for all 4 elems)
    // row' = w*128 + rt*16 + q*4 + r -> col_nat = r*256 + w*32 + rt*4 + q
    int colnat = (row & 3) * 256 + (row >> 7) * 32 + ((row >> 4) & 7) * 4 +
                 ((row >> 2) & 3);
    unsigned long long pk = 0;
#pragma unroll
    for (int j = 0; j < 4; ++j) {
      int k = (int)((i0 + j) & 255);
      pk |= (unsigned long long)f2bf(Wh[(size_t)k * 1024 + colnat]) << (16 * j);
    }
    *(unsigned long long*)&WhP[i0] = pk;
  }
}

// ---------------------------------------------------------------- xg = x@Wi+b
#define XKP 40  // LDS k-pitch (shorts): 80B rows -> 16B-aligned b128, ~2-way banks
__global__ __launch_bounds__(256) void xg_gemm(const unsigned short* __restrict__ xbf,
                                               const unsigned short* __restrict__ WiT,
                                               const float* __restrict__ bias,
                                               unsigned short* __restrict__ xg) {
  __shared__ unsigned short As[128 * XKP];
  __shared__ unsigned short Bs[128 * XKP];
  const int tid = threadIdx.x;
  const int n0 = blockIdx.x * 128, m0 = blockIdx.y * 128;
  const int wave = tid >> 6, lane = tid & 63, quad = lane >> 4, l16 = lane & 15;
  const int wm = wave >> 1, wn = wave & 1;

  float4v acc[4][4];
#pragma unroll
  for (int i = 0; i < 4; ++i)
#pragma unroll
    for (int j = 0; j < 4; ++j) acc[i][j] = (float4v){0.f, 0.f, 0.f, 0.f};

  const int rr = tid >> 2, c8 = (tid & 3) * 8;  // staging coords (16B per thread)
  for (int k0 = 0; k0 < 256; k0 += 32) {
#pragma unroll
    for (int pp = 0; pp < 2; ++pp) {
      int r = pp * 64 + rr;
      *(uint4*)&As[r * XKP + c8] = *(const uint4*)&xbf[(size_t)(m0 + r) * 256 + k0 + c8];
      *(uint4*)&Bs[r * XKP + c8] = *(const uint4*)&WiT[(size_t)(n0 + r) * 256 + k0 + c8];
    }
    __syncthreads();
#pragma unroll
    for (int mt = 0; mt < 4; ++mt) {
      short8 af = *(const short8*)&As[(wm * 64 + mt * 16 + l16) * XKP + quad * 8];
#pragma unroll
      for (int nt = 0; nt < 4; ++nt) {
        short8 bf = *(const short8*)&Bs[(wn * 64 + nt * 16 + l16) * XKP + quad * 8];
        acc[mt][nt] = __builtin_amdgcn_mfma_f32_16x16x32_bf16(af, bf, acc[mt][nt], 0, 0, 0);
      }
    }
    __syncthreads();
  }
  // epilogue: +bias, bf16 store, PERMUTED layout for the scan:
  //   xg[((b*512 + t)*256 + u)*4 + gate]   (4 gates of a unit contiguous, 8B)
#pragma unroll
  for (int nt = 0; nt < 4; ++nt) {
    int col = n0 + wn * 64 + nt * 16 + l16;
    int gate = col >> 8, u = col & 255;
    float bv = bias[col];
#pragma unroll
    for (int mt = 0; mt < 4; ++mt) {
#pragma unroll
      for (int r = 0; r < 4; ++r) {
        int row = m0 + wm * 64 + mt * 16 + quad * 4 + r;
        int b = row >> 9, t = row & 511;
        xg[(((size_t)b * 512 + t) * 256 + u) * 4 + gate] = f2bf(acc[mt][nt][r] + bv);
      }
    }
  }
}

// ---------------------------------------------------------------- LSTM scan
// 64 WGs, one batch each. 512 threads = 8 waves, EXACTLY 2 waves/SIMD
// (amdgpu_waves_per_eu(2,2) -> 256-VGPR budget; kernel peak ~217).
// Wave w, pass/tile p: p<nS streamed, p in [nS,nS+4) registers, rest LDS.
__global__ __launch_bounds__(512)
__attribute__((amdgpu_waves_per_eu(2, 2)))
void lstm_scan(const unsigned short* __restrict__ WhP,  // [1024][256] bf16
               const unsigned short* __restrict__ xg,   // [b][t][u][gate] bf16
               unsigned short* __restrict__ hout) {
  __shared__ unsigned short WhL[19 * 4096];     // 19 slots x 8KB = 155648 B
  __shared__ unsigned short hA[2][256];         // 1 KB, double-buffered h
  const int tid = threadIdx.x;
  const int b = blockIdx.x;  // batch
  const int wave = __builtin_amdgcn_readfirstlane(tid >> 6);
  const int lane = tid & 63, quad = lane >> 4, l16 = lane & 15;
  // wave-uniform partition: waves 0-2: 1 stream + 3 LDS; waves 3-7: 2 + 2.
  const int nS = (wave < 3) ? 1 : 2;
  const int nL = 4 - nS;
  const int slotBase = (wave < 3) ? wave * 3 : 9 + (wave - 3) * 2;

  // ---- 4 register tiles: rt = nS + j
  short8 frA[4][8];
#pragma unroll
  for (int j = 0; j < 4; ++j) {
    const unsigned short* src =
        WhP + ((size_t)wave * 128 + (nS + j) * 16 + l16) * 256 + quad * 8;
#pragma unroll
    for (int kt = 0; kt < 8; ++kt)
      frA[j][kt] = *(const short8*)&src[kt * 32];
  }
  // ---- LDS tiles: rt = nS+4+j -> slot slotBase+j, XOR-swizzled
  for (int j = 0; j < nL; ++j) {
    int rt = nS + 4 + j;
    for (int i = 0; i < 8; ++i) {
      int chunk = i * 64 + lane;         // 512 16B-chunks per tile
      int rw = chunk >> 5, ch = chunk & 31;
      uint4 v = *(const uint4*)&WhP[((size_t)wave * 128 + rt * 16 + rw) * 256 + ch * 8];
      *(uint4*)((char*)WhL + (slotBase + j) * 8192 + rw * 512 +
                ((ch * 16) ^ ((rw & 7) << 4))) = v;
    }
  }
  ((unsigned short*)hA)[tid] = 0;        // h_{-1} = 0 (both buffers; 512 shorts)

  const bool act = (l16 < 8);
  const int u = wave * 32 + l16 * 4 + quad;    // this lane's unit (if act)
  const unsigned short* xgp = xg + ((size_t)b * 512 * 256 + u) * 4;
  unsigned short* houtp = hout + (size_t)b * 512 * 256 + u;
  const char* ldsT = (const char*)WhL + slotBase * 8192 + l16 * 512;
  const unsigned short* sp0 = WhP + ((size_t)wave * 128 + 0 * 16 + l16) * 256 + quad * 8;
  const unsigned short* sp1 = WhP + ((size_t)wave * 128 + 1 * 16 + l16) * 256 + quad * 8;
  float c = 0.f;

  // prologue: prefetch stream tile 0 (consumed in pass 0 of t=0)
  short8 sb[8];
#pragma unroll
  for (int kt = 0; kt < 8; ++kt) sb[kt] = *(const short8*)&sp0[kt * 32];
  __syncthreads();

  for (int t = 0; t < 512; ++t) {
    // xg(t): 4 gates of this lane's unit, 8B (consumed at step end)
    unsigned long long xv = 0;
    if (act) xv = *(const unsigned long long*)(xgp + (size_t)t * 1024);

    // h_{t-1} broadcast fragments (conflict-free broadcast reads)
    const char* hbuf = (const char*)hA[t & 1];
    short8 hb8[8];
#pragma unroll
    for (int kt = 0; kt < 8; ++kt)
      hb8[kt] = *(const short8*)(hbuf + kt * 64 + quad * 16);

    float4v g4 = (float4v){0.f, 0.f, 0.f, 0.f};

    // ---- pass 0: stream tile 0 (prefetched across the barrier)
    {
      float4v a = (float4v){0.f, 0.f, 0.f, 0.f};
#pragma unroll
      for (int kt = 0; kt < 8; ++kt)
        a = __builtin_amdgcn_mfma_f32_16x16x32_bf16(sb[kt], hb8[kt], a, 0, 0, 0);
      if (l16 == 0) g4 = a;
    }
    // ---- pass 1 (2-stream waves only): reuse sb; co-wave covers the stall
    if (nS == 2) {
#pragma unroll
      for (int kt = 0; kt < 8; ++kt) sb[kt] = *(const short8*)&sp1[kt * 32];
      float4v a = (float4v){0.f, 0.f, 0.f, 0.f};
#pragma unroll
      for (int kt = 0; kt < 8; ++kt)
        a = __builtin_amdgcn_mfma_f32_16x16x32_bf16(sb[kt], hb8[kt], a, 0, 0, 0);
      if (l16 == 1) g4 = a;
    }
    // ---- register passes: tiles rt = nS + j
#pragma unroll
    for (int j = 0; j < 4; ++j) {
      float4v a = (float4v){0.f, 0.f, 0.f, 0.f};
#pragma unroll
      for (int kt = 0; kt < 8; ++kt)
        a = __builtin_amdgcn_mfma_f32_16x16x32_bf16(frA[j][kt], hb8[kt], a, 0, 0, 0);
      if (l16 == nS + j) g4 = a;
    }
    // ---- LDS passes: tiles rt = nS+4+j
    for (int j = 0; j < nL; ++j) {
      float4v a = (float4v){0.f, 0.f, 0.f, 0.f};
#pragma unroll
      for (int kt = 0; kt < 8; ++kt) {
        short8 al = *(const short8*)(ldsT + j * 8192 +
                                     ((kt * 64 + quad * 16) ^ ((l16 & 7) << 4)));
        a = __builtin_amdgcn_mfma_f32_16x16x32_bf16(al, hb8[kt], a, 0, 0, 0);
      }
      if (l16 == nS + 4 + j) g4 = a;
    }

    // ---- gates (active lanes own one unit each)
    if (act) {
      float gi = g4[0] + bf2f((unsigned short)(xv));
      float gf = g4[1] + bf2f((unsigned short)(xv >> 16));
      float gG = g4[2] + bf2f((unsigned short)(xv >> 32));
      float go = g4[3] + bf2f((unsigned short)(xv >> 48));
      float cc = sigm(gf) * c + sigm(gi) * tanh_f(gG);
      c = cc;
      unsigned short h16 = f2bf(sigm(go) * tanh_f(cc));
      hA[(t + 1) & 1][u] = h16;          // next buffer (disjoint from readers)
      houtp[(size_t)t * 256] = h16;      // h history for attention
    }
    // ---- prefetch stream tile 0 for next step (hides under gates+barrier)
#pragma unroll
    for (int kt = 0; kt < 8; ++kt) sb[kt] = *(const short8*)&sp0[kt * 32];
    __syncthreads();                     // ONE barrier per step
  }
}

// --------------------------------------------------- attention + head (fused)
__global__ __launch_bounds__(256) void attn_head(
    const unsigned short* __restrict__ hout,
    const float* __restrict__ Wq, const float* __restrict__ bq,
    const float* __restrict__ Wk, const float* __restrict__ bk,
    const float* __restrict__ Wv, const float* __restrict__ bv,
    const float* __restrict__ Wo, const float* __restrict__ bo,
    const float* __restrict__ W1, const float* __restrict__ b1,
    const float* __restrict__ W2, const float* __restrict__ b2,
    float* __restrict__ out) {
  __shared__ float h0S[256], q0S[256], red[256], usS[256], sS[512], hb4[4][256];
  __shared__ float oS[256], o1S[256], zS[32], cbS;
  const int b = blockIdx.x, tid = threadIdx.x, wave = tid >> 6, lane = tid & 63;
  const size_t hb_base = (size_t)b * 512 * 256;

  // ---- q0 = h0@Wq+bq ; u = Wk@(scale*q0) ; cb = scale*q0.bk
  h0S[tid] = bf2f(hout[hb_base + tid]);
  __syncthreads();
  float a = 0.f;
  for (int k = 0; k < 256; ++k) a += h0S[k] * Wq[(size_t)k * 256 + tid];
  q0S[tid] = a + bq[tid];
  __syncthreads();
  red[tid] = q0S[tid] * bk[tid];
  __syncthreads();
  for (int s = 128; s > 0; s >>= 1) {
    if (tid < s) red[tid] += red[tid + s];
    __syncthreads();
  }
  if (tid == 0) cbS = 0.0625f * red[0];
  float acq = 0.f;
  const float* wr = &Wk[(size_t)tid * 256];
  for (int e = 0; e < 256; e += 4) {
    float4 w = *(const float4*)&wr[e];
    acq += w.x * q0S[e] + w.y * q0S[e + 1] + w.z * q0S[e + 2] + w.w * q0S[e + 3];
  }
  usS[tid] = 0.0625f * acq;
  __syncthreads();

  // ---- scores = u.h[b,t]+cb -> softmax -> hbar = sum attn*h
  const float u0 = usS[lane * 4 + 0], u1 = usS[lane * 4 + 1];
  const float u2 = usS[lane * 4 + 2], u3 = usS[lane * 4 + 3];
  const float cbv = cbS;
  for (int i = 0; i < 128; ++i) {
    int t = i * 4 + wave;
    unsigned long long hv = *(const unsigned long long*)&hout[hb_base + (size_t)t * 256 + lane * 4];
    unsigned lo = (unsigned)hv, hi = (unsigned)(hv >> 32);
    float p = u0 * bcl(lo) + u1 * bch(lo) + u2 * bcl(hi) + u3 * bch(hi);
    for (int m = 1; m < 64; m <<= 1) p += __shfl_xor(p, m, 64);
    if (lane == 0) sS[t] = p + cbv;
  }
  __syncthreads();
  red[tid] = fmaxf(sS[tid], sS[tid + 256]);
  __syncthreads();
  for (int s = 128; s > 0; s >>= 1) {
    if (tid < s) red[tid] = fmaxf(red[tid], red[tid + s]);
    __syncthreads();
  }
  float mx = red[0];
  __syncthreads();
  float e0 = __expf(sS[tid] - mx), e1 = __expf(sS[tid + 256] - mx);
  sS[tid] = e0; sS[tid + 256] = e1;
  red[tid] = e0 + e1;
  __syncthreads();
  for (int s = 128; s > 0; s >>= 1) {
    if (tid < s) red[tid] += red[tid + s];
    __syncthreads();
  }
  float inv = 1.f / red[0];
  float a0 = 0.f, a1 = 0.f, a2 = 0.f, a3 = 0.f;
  const int d0 = lane * 4;
  for (int i = 0; i < 128; ++i) {
    int t = wave * 128 + i;
    float w = sS[t];
    unsigned long long hv = *(const unsigned long long*)&hout[hb_base + (size_t)t * 256 + d0];
    unsigned lo = (unsigned)hv, hi = (unsigned)(hv >> 32);
    a0 += w * bcl(lo); a1 += w * bch(lo); a2 += w * bcl(hi); a3 += w * bch(hi);
  }
  hb4[wave][d0] = a0; hb4[wave][d0 + 1] = a1; hb4[wave][d0 + 2] = a2; hb4[wave][d0 + 3] = a3;
  __syncthreads();
  h0S[tid] = (hb4[0][tid] + hb4[1][tid] + hb4[2][tid] + hb4[3][tid]) * inv;  // hbar
  __syncthreads();

  // ---- head: o0=hbar@Wv+bv ; o1=o0@Wo+bo ; z=relu(o1@W1+b1) ; out=z@W2+b2
  a = 0.f;
  for (int k = 0; k < 256; ++k) a += h0S[k] * Wv[(size_t)k * 256 + tid];
  oS[tid] = a + bv[tid];
  __syncthreads();
  a = 0.f;
  for (int k = 0; k < 256; ++k) a += oS[k] * Wo[(size_t)k * 256 + tid];
  o1S[tid] = a + bo[tid];
  __syncthreads();
  if (tid < 32) {
    a = 0.f;
    for (int k = 0; k < 256; ++k) a += o1S[k] * W1[k * 32 + tid];
    zS[tid] = fmaxf(a + b1[tid], 0.f);
  }
  __syncthreads();
  if (tid < 3) {
    a = 0.f;
    for (int j = 0; j < 32; ++j) a += zS[j] * W2[j * 3 + tid];
    out[b * 3 + tid] = a + b2[tid];
  }
}

// ---------------------------------------------------------------- launch
extern "C" void kernel_launch(void* const* d_in, const int* in_sizes, int n_in,
                              void* d_out, int out_size, void* d_ws, size_t ws_size,
                              hipStream_t stream) {
  const float* x  = (const float*)d_in[0];
  const float* Wi = (const float*)d_in[1];
  const float* Wh = (const float*)d_in[2];
  const float* bG = (const float*)d_in[3];
  const float* Wq = (const float*)d_in[4];
  const float* bq = (const float*)d_in[5];
  const float* Wk = (const float*)d_in[6];
  const float* bk = (const float*)d_in[7];
  const float* Wv = (const float*)d_in[8];
  const float* bv = (const float*)d_in[9];
  const float* Wo = (const float*)d_in[10];
  const float* bo = (const float*)d_in[11];
  const float* W1 = (const float*)d_in[12];
  const float* b1 = (const float*)d_in[13];
  const float* W2 = (const float*)d_in[14];
  const float* b2 = (const float*)d_in[15];
  float* out = (float*)d_out;
  char* ws = (char*)d_ws;

  unsigned short* xg   = (unsigned short*)(ws);              // 67,108,864 B
  unsigned short* hout = (unsigned short*)(ws + 67108864);   // 16,777,216 B
  unsigned short* xbf  = (unsigned short*)(ws + 83886080);   // 16,777,216 B
  unsigned short* WiT  = (unsigned short*)(ws + 100663296);  //    524,288 B
  unsigned short* WhP  = (unsigned short*)(ws + 101187584);  //    524,288 B
  // total ~101.7 MB of workspace

  prep_all<<<dim3(8704), dim3(256), 0, stream>>>(x, Wi, Wh, xbf, WiT, WhP);
  xg_gemm<<<dim3(8, 256), dim3(256), 0, stream>>>(xbf, WiT, bG, xg);
  lstm_scan<<<dim3(64), dim3(512), 0, stream>>>(WhP, xg, hout);
  attn_head<<<dim3(64), dim3(256), 0, stream>>>(hout, Wq, bq, Wk, bk, Wv, bv,
                                                Wo, bo, W1, b1, W2, b2, out);
}